// Round 6
// baseline (249.815 us; speedup 1.0000x reference)
//
#include <hip/hip_runtime.h>

typedef unsigned short u16;
typedef __attribute__((ext_vector_type(4))) unsigned int u32x4;
typedef __attribute__((ext_vector_type(4))) float f32x4;
typedef __attribute__((ext_vector_type(8))) __bf16 bf16x8;

// Problem constants (fixed by the reference).
constexpr int BATCH = 2;
constexpr int NV    = 20000;
constexpr int ND    = 8;
constexpr int CH    = 16;
constexpr int NF    = 16;
constexpr int NVD   = NV * ND;        // 160000 rows of y_flat per batch
constexpr int NCHUNK = 36;            // 32 conv chunks + 4 center chunks (K=1152 total)
constexpr int MTOT  = BATCH * NV;     // 40000 GEMM rows
constexpr int BSTR  = 40;             // padded B row stride in bf16 (32+8)
constexpr int KSPLIT_CH = 18;         // chunks per K-slice (2 slices)

// ws layout (bytes):
//   [0, 10,240,000)              y16 : bf16 [B][NVD][CH]
//   [10,240,000, 10,534,912)     k2c : bf16 [36][128][32]   (chunk-major weights)
//   [10,534,912, 51,494,912)     pb  : f32  [2][128][40000] (K-slice partials, col-major)
constexpr size_t Y16_OFF_B = 0;
constexpr size_t K2C_OFF_B = 10240000;
constexpr size_t PB_OFF_B  = 10534912;   // total ws needed = 51,494,912 B

__device__ __forceinline__ u16 f2bf(float x) {
    unsigned int u = __float_as_uint(x);
    unsigned int r = (u + 0x7fffu + ((u >> 16) & 1u)) >> 16;   // RNE
    return (u16)r;
}
__device__ __forceinline__ unsigned int pack2bf(float a, float b) {
    return (unsigned int)f2bf(a) | ((unsigned int)f2bf(b) << 16);
}

// ---------------- P1: prep — y fp32 -> y16 bf16 table ----------------
__global__ __launch_bounds__(256) void prep(const float* __restrict__ y,
                                            u16* __restrict__ y16) {
    int tid = blockIdx.x * 256 + threadIdx.x;       // [0, 320000)
    const float4* src = (const float4*)(y + (size_t)tid * 16);
    float4 v0 = src[0], v1 = src[1], v2 = src[2], v3 = src[3];
    u32x4 lo = {pack2bf(v0.x, v0.y), pack2bf(v0.z, v0.w), pack2bf(v1.x, v1.y), pack2bf(v1.z, v1.w)};
    u32x4 hi = {pack2bf(v2.x, v2.y), pack2bf(v2.z, v2.w), pack2bf(v3.x, v3.y), pack2bf(v3.z, v3.w)};
    u16* yd = y16 + (size_t)tid * 16;
    *(u32x4*)(yd)     = lo;
    *(u32x4*)(yd + 8) = hi;
}

// ---------------- P2: build rotated+extended weight matrix K2c ----------------
__global__ __launch_bounds__(256) void k2_build(const float* __restrict__ kern,
                                                const float* __restrict__ ck,
                                                u16* __restrict__ k2c) {
    int e = blockIdx.x * 256 + threadIdx.x;   // [0, 36*4096)
    int i = e & 4095;
    int kc = e >> 12;
    int n = i >> 5, kk = i & 31;
    int k = kc * 32 + kk;
    int w = n >> 4, f = n & 15;
    float val;
    if (k < 1024) {
        int r = k >> 7, dd = (k >> 4) & 7, c = k & 15;
        int d = (dd - w) & 7;
        val = kern[((r * 8 + d) * 16 + c) * 16 + f];
    } else {
        int ke = k - 1024;
        int d = ke >> 4, c = ke & 15;
        val = (d == w) ? ck[c * 16 + f] : 0.f;
    }
    k2c[e] = f2bf(val);
}

// ---------------- F: FUSED gather + barycentric + K-slice GEMM ----------------
// K-SPLIT x2 (r5 lesson: grid 625 = 2.4 blocks/CU capped occupancy at ~10 waves/CU,
// latency-bound on random gathers). Two blocks per output tile: slice = bid&1 owns
// chunks [slice*18, slice*18+18). Grid 1250 -> ~20 waves/CU. Partials go to pb
// col-major (f32x4 coalesced); combine_max does +bias/relu/max.
// Pipeline state in NAMED registers (rule #20), even/odd phase structure from r5.
__global__ __launch_bounds__(256) void fused_gather_gemm(const u16* __restrict__ y16,
                                                         const int* __restrict__ contrib,
                                                         const float* __restrict__ wbary,
                                                         const int* __restrict__ angles,
                                                         const u16* __restrict__ k2c,
                                                         float* __restrict__ pb) {
    __shared__ __align__(16) u16 Bb[2][128 * BSTR];   // 20,480 B
    const int t = threadIdx.x;
    const int s  = blockIdx.x & 1;           // K-slice
    const int kcBeg = s * KSPLIT_CH;
    const int kcEnd = kcBeg + KSPLIT_CH;
    const int w = t >> 6, lane = t & 63;
    const int lrow = lane & 15, lq = lane >> 4;
    const int s_p = lq >> 1;                 // rd parity this lane owns
    const int h8  = (lq & 1) * 8;            // ch-half element offset
    const int m0 = (blockIdx.x >> 1) * 64;
    const int arow = m0 + w * 16 + lrow;     // GEMM row == gather row (same lane!)
    const int b_p = (arow >= NV);
    const int v_p = arow - b_p * NV;
    const u16* __restrict__ yb = y16 + (size_t)b_p * NVD * CH + h8;  // batch table + half
    const int mb0 = v_p * 192 + s_p * 3;     // meta element base; idx(kc) = mb0 + kc*6
    const int sn = t >> 1, sh = (t & 1) * 16;

    // pipeline state — ALL named scalars/vectors (no runtime-indexed arrays)
    int   ce0, ce1, ce2, ae0, ae1, ae2;  float we0, we1, we2;   // meta, even chunks
    int   co0, co1, co2, ao0, ao1, ao2;  float wo0, wo1, wo2;   // meta, odd chunks
    u32x4 ge0, ge1, ge2;  float ve0, ve1, ve2;                  // gathers, even
    u32x4 go0, go1, go2;  float vo0, vo1, vo2;                  // gathers, odd
    u32x4 bne0, bne1, bno0, bno1;                               // B staging regs

    f32x4 acc[8];
    #pragma unroll
    for (int nt = 0; nt < 8; ++nt) acc[nt] = (f32x4){0.f, 0.f, 0.f, 0.f};

#define META_ISSUE(S, KC_) { const int o_ = mb0 + (KC_) * 6;                       \
    c##S##0 = contrib[o_]; c##S##1 = contrib[o_ + 1]; c##S##2 = contrib[o_ + 2];   \
    a##S##0 = angles[o_];  a##S##1 = angles[o_ + 1];  a##S##2 = angles[o_ + 2];    \
    w##S##0 = wbary[o_];   w##S##1 = wbary[o_ + 1];   w##S##2 = wbary[o_ + 2]; }

#define G_ISSUE(S, KC_) {                                                          \
    if ((KC_) < 32) {                                                              \
        g##S##0 = *(const u32x4*)(yb + (size_t)((unsigned)c##S##0 * 128u +         \
                                                (unsigned)a##S##0 * 16u));         \
        g##S##1 = *(const u32x4*)(yb + (size_t)((unsigned)c##S##1 * 128u +         \
                                                (unsigned)a##S##1 * 16u));         \
        g##S##2 = *(const u32x4*)(yb + (size_t)((unsigned)c##S##2 * 128u +         \
                                                (unsigned)a##S##2 * 16u));         \
        v##S##0 = w##S##0; v##S##1 = w##S##1; v##S##2 = w##S##2;                   \
    } else {                                                                       \
        g##S##0 = *(const u32x4*)(yb + (size_t)((unsigned)v_p * 128u +             \
                                      (unsigned)(2 * ((KC_) - 32) + s_p) * 16u));  \
    } }

#define COMBINE(S, KC_, A_) {                                                      \
    if ((KC_) < 32) {                                                              \
        float ac_[8];                                                              \
        _Pragma("unroll") for (int x_ = 0; x_ < 8; ++x_) ac_[x_] = 0.f;            \
        _Pragma("unroll")                                                          \
        for (int q_ = 0; q_ < 4; ++q_) {                                           \
            unsigned u0_ = g##S##0[q_], u1_ = g##S##1[q_], u2_ = g##S##2[q_];      \
            ac_[2 * q_]     += v##S##0 * __uint_as_float(u0_ << 16);               \
            ac_[2 * q_ + 1] += v##S##0 * __uint_as_float(u0_ & 0xffff0000u);       \
            ac_[2 * q_]     += v##S##1 * __uint_as_float(u1_ << 16);               \
            ac_[2 * q_ + 1] += v##S##1 * __uint_as_float(u1_ & 0xffff0000u);       \
            ac_[2 * q_]     += v##S##2 * __uint_as_float(u2_ << 16);               \
            ac_[2 * q_ + 1] += v##S##2 * __uint_as_float(u2_ & 0xffff0000u);       \
        }                                                                          \
        u32x4 o_;                                                                  \
        _Pragma("unroll") for (int q_ = 0; q_ < 4; ++q_)                           \
            o_[q_] = pack2bf(ac_[2 * q_], ac_[2 * q_ + 1]);                        \
        A_ = *(bf16x8*)&o_;                                                        \
    } else { u32x4 o_ = g##S##0; A_ = *(bf16x8*)&o_; } }

    // ---- prologue (kcBeg is even for both slices: 0 or 18) ----
    META_ISSUE(e, kcBeg); META_ISSUE(o, kcBeg + 1);
    {   // stage B(kcBeg) directly
        const u32x4* src = (const u32x4*)(k2c + (size_t)kcBeg * 4096 + sn * 32 + sh);
        u32x4 b0 = src[0], b1 = src[1];
        u16* dst = &Bb[0][sn * BSTR + sh];
        *(u32x4*)(dst)     = b0;
        *(u32x4*)(dst + 8) = b1;
    }
    G_ISSUE(e, kcBeg); META_ISSUE(e, kcBeg + 2);   // meta(kcBeg) consumed -> refill
    G_ISSUE(o, kcBeg + 1);                         // meta(kcBeg+1) consumed
    {   // B(kcBeg+1) -> bno (consumed by p=0 even-phase ds_write)
        const u32x4* src = (const u32x4*)(k2c + (size_t)(kcBeg + 1) * 4096 + sn * 32 + sh);
        bno0 = src[0]; bno1 = src[1];
    }

    // ---- main loop: 9 pairs of chunks; all register refs compile-time static ----
    for (int p = 0; p < KSPLIT_CH / 2; ++p) {
        const int k0 = kcBeg + 2 * p, k1 = k0 + 1;

        // ===== even chunk k0 =====
        __syncthreads();                                   // Bb[0] = B(k0) visible
        if (k0 + 2 < kcEnd) {                              // B issue (oldest first)
            const u32x4* src = (const u32x4*)(k2c + (size_t)(k0 + 2) * 4096 + sn * 32 + sh);
            bne0 = src[0]; bne1 = src[1];
        }
        bf16x8 aev;
        COMBINE(e, k0, aev);                               // waits gathers issued at k0-2
        if (k0 + 2 < kcEnd) G_ISSUE(e, k0 + 2);            // meta issued at k0-1
        if (k0 + 3 < kcEnd && k0 + 3 < 32) META_ISSUE(o, k0 + 3);
        {
            bf16x8 bf[8];
            #pragma unroll
            for (int nt = 0; nt < 8; ++nt)
                bf[nt] = *(const bf16x8*)(&Bb[0][(nt * 16 + lrow) * BSTR + lq * 8]);
            #pragma unroll
            for (int nt = 0; nt < 8; ++nt)
                acc[nt] = __builtin_amdgcn_mfma_f32_16x16x32_bf16(aev, bf[nt], acc[nt], 0, 0, 0);
        }
        {   // stage B(k0+1) into Bb[1] (regs loaded at k0-1); k0+1 < kcEnd always
            u16* dst = &Bb[1][sn * BSTR + sh];
            *(u32x4*)(dst)     = bno0;
            *(u32x4*)(dst + 8) = bno1;
        }

        // ===== odd chunk k1 =====
        __syncthreads();                                   // Bb[1] = B(k1) visible
        if (k1 + 2 < kcEnd) {
            const u32x4* src = (const u32x4*)(k2c + (size_t)(k1 + 2) * 4096 + sn * 32 + sh);
            bno0 = src[0]; bno1 = src[1];
        }
        bf16x8 aov;
        COMBINE(o, k1, aov);
        if (k1 + 2 < kcEnd) G_ISSUE(o, k1 + 2);
        if (k1 + 3 < kcEnd && k1 + 3 < 32) META_ISSUE(e, k1 + 3);
        {
            bf16x8 bf[8];
            #pragma unroll
            for (int nt = 0; nt < 8; ++nt)
                bf[nt] = *(const bf16x8*)(&Bb[1][(nt * 16 + lrow) * BSTR + lq * 8]);
            #pragma unroll
            for (int nt = 0; nt < 8; ++nt)
                acc[nt] = __builtin_amdgcn_mfma_f32_16x16x32_bf16(aov, bf[nt], acc[nt], 0, 0, 0);
        }
        if (k1 + 1 < kcEnd) {                              // stage B(k1+1) into Bb[0]
            u16* dst = &Bb[0][sn * BSTR + sh];
            *(u32x4*)(dst)     = bne0;
            *(u32x4*)(dst + 8) = bne1;
        }
    }
#undef META_ISSUE
#undef G_ISSUE
#undef COMBINE

    // partial store, col-major pb[s][n][row]: f32x4 over 4 consecutive rows -> coalesced
    float* pbs = pb + (size_t)(s * 128) * MTOT;
    #pragma unroll
    for (int nt = 0; nt < 8; ++nt) {
        *(f32x4*)(pbs + (size_t)(nt * 16 + lrow) * MTOT + m0 + w * 16 + lq * 4) = acc[nt];
    }
}

// ---------------- E: combine K-slices + bias + relu + max over w ----------------
// one thread per (row, f-half): 128 fully-coalesced loads (lane pairs share rows),
// static m[8] indexing (full unroll), 32 B contiguous store per thread.
__global__ __launch_bounds__(256) void combine_max(const float* __restrict__ pb,
                                                   const float* __restrict__ bias,
                                                   float* __restrict__ out) {
    int tid = blockIdx.x * 256 + threadIdx.x;   // [0, 80000)
    if (tid >= 2 * MTOT) return;
    int row = tid >> 1, half = tid & 1;
    const float* p0 = pb + row;
    const float* p1 = pb + (size_t)128 * MTOT + row;
    float bs[8], m[8];
    #pragma unroll
    for (int j = 0; j < 8; ++j) { bs[j] = bias[half * 8 + j]; m[j] = 0.f; }
    #pragma unroll
    for (int w = 0; w < 8; ++w) {
        #pragma unroll
        for (int j = 0; j < 8; ++j) {
            int n = w * 16 + half * 8 + j;
            float v = p0[(size_t)n * MTOT] + p1[(size_t)n * MTOT] + bs[j];
            m[j] = fmaxf(m[j], v);
        }
    }
    float4 o0 = {m[0], m[1], m[2], m[3]};
    float4 o1 = {m[4], m[5], m[6], m[7]};
    float* dst = out + (size_t)row * NF + half * 8;
    *(float4*)(dst)     = o0;
    *(float4*)(dst + 4) = o1;
}

extern "C" void kernel_launch(void* const* d_in, const int* in_sizes, int n_in,
                              void* d_out, int out_size, void* d_ws, size_t ws_size,
                              hipStream_t stream) {
    const float* y      = (const float*)d_in[0];
    const int*   contrib= (const int*)d_in[1];
    const float* wbary  = (const float*)d_in[2];
    const int*   angles = (const int*)d_in[3];
    const float* kern   = (const float*)d_in[4];
    const float* ck     = (const float*)d_in[5];
    const float* bias   = (const float*)d_in[6];
    float* out = (float*)d_out;

    u16*   y16 = (u16*)((char*)d_ws + Y16_OFF_B);
    u16*   k2c = (u16*)((char*)d_ws + K2C_OFF_B);
    float* pb  = (float*)((char*)d_ws + PB_OFF_B);   // needs ws_size >= 51,494,912 B

    prep<<<1250, 256, 0, stream>>>(y, y16);
    k2_build<<<(NCHUNK * 4096) / 256, 256, 0, stream>>>(kern, ck, k2c);
    fused_gather_gemm<<<2 * (MTOT / 64), 256, 0, stream>>>(y16, contrib, wbary, angles,
                                                           k2c, pb);          // 1250 blocks
    combine_max<<<(2 * MTOT + 255) / 256, 256, 0, stream>>>(pb, bias, out);   // 313 blocks
}

// Round 7
// 239.836 us; speedup vs baseline: 1.0416x; 1.0416x over previous
//
#include <hip/hip_runtime.h>

typedef unsigned short u16;
typedef __attribute__((ext_vector_type(4))) unsigned int u32x4;
typedef __attribute__((ext_vector_type(4))) float f32x4;
typedef __attribute__((ext_vector_type(8))) __bf16 bf16x8;

// Problem constants (fixed by the reference).
constexpr int BATCH = 2;
constexpr int NV    = 20000;
constexpr int ND    = 8;
constexpr int CH    = 16;
constexpr int NF    = 16;
constexpr int NVD   = NV * ND;        // 160000 rows of y_flat per batch
constexpr int NCHUNK = 36;            // 32 conv chunks + 4 center chunks (K=1152 total)
constexpr int MTOT  = BATCH * NV;     // 40000 GEMM rows
constexpr int BSTR  = 40;             // padded B row stride in bf16 (32+8)
constexpr int KSPLIT_CH = 18;         // chunks per K-slice (2 slices)
constexpr int PREP_BLOCKS = 1250;     // prep part of merged prep_k2
constexpr int K2_BLOCKS   = (NCHUNK * 4096) / 256;   // 576

// ws layout (bytes):
//   [0, 10,240,000)              y16 : bf16 [B][NVD][CH]
//   [10,240,000, 10,534,912)     k2c : bf16 [36][128][32]   (chunk-major weights)
//   [10,534,912, 51,494,912)     pb  : f32  [2][128][40000] (K-slice partials, col-major)
constexpr size_t Y16_OFF_B = 0;
constexpr size_t K2C_OFF_B = 10240000;
constexpr size_t PB_OFF_B  = 10534912;   // total ws needed = 51,494,912 B

__device__ __forceinline__ u16 f2bf(float x) {
    unsigned int u = __float_as_uint(x);
    unsigned int r = (u + 0x7fffu + ((u >> 16) & 1u)) >> 16;   // RNE
    return (u16)r;
}
__device__ __forceinline__ unsigned int pack2bf(float a, float b) {
    return (unsigned int)f2bf(a) | ((unsigned int)f2bf(b) << 16);
}

// ---------------- P: merged prep (y->y16) + k2c build (one launch) ----------------
__global__ __launch_bounds__(256) void prep_k2(const float* __restrict__ y,
                                               u16* __restrict__ y16,
                                               const float* __restrict__ kern,
                                               const float* __restrict__ ck,
                                               u16* __restrict__ k2c) {
    int bid = blockIdx.x;
    if (bid < PREP_BLOCKS) {
        int tid = bid * 256 + threadIdx.x;          // [0, 320000)
        const float4* src = (const float4*)(y + (size_t)tid * 16);
        float4 v0 = src[0], v1 = src[1], v2 = src[2], v3 = src[3];
        u32x4 lo = {pack2bf(v0.x, v0.y), pack2bf(v0.z, v0.w), pack2bf(v1.x, v1.y), pack2bf(v1.z, v1.w)};
        u32x4 hi = {pack2bf(v2.x, v2.y), pack2bf(v2.z, v2.w), pack2bf(v3.x, v3.y), pack2bf(v3.z, v3.w)};
        u16* yd = y16 + (size_t)tid * 16;
        *(u32x4*)(yd)     = lo;
        *(u32x4*)(yd + 8) = hi;
    } else {
        int e = (bid - PREP_BLOCKS) * 256 + threadIdx.x;   // [0, 36*4096)
        int i = e & 4095;
        int kc = e >> 12;
        int n = i >> 5, kk = i & 31;
        int k = kc * 32 + kk;
        int w = n >> 4, f = n & 15;
        float val;
        if (k < 1024) {
            int r = k >> 7, dd = (k >> 4) & 7, c = k & 15;
            int d = (dd - w) & 7;
            val = kern[((r * 8 + d) * 16 + c) * 16 + f];
        } else {
            int ke = k - 1024;
            int d = ke >> 4, c = ke & 15;
            val = (d == w) ? ck[c * 16 + f] : 0.f;
        }
        k2c[e] = f2bf(val);
    }
}

// ---------------- F: FUSED gather + barycentric + K-slice GEMM (depth-3 pipeline) ----------------
// r6 lesson: fused kernel is gather-LATENCY serialized (phase >= miss-latency / depth).
// Depth 2 -> 3: slots A/B/C, gather lead 3 chunks, meta lead 6 chunks. All pipeline
// state in NAMED registers (rule #20); 6-chunk unrolled body makes every slot ref and
// LDS/B-reg parity compile-time static (kcBeg and base are even for both slices).
__global__ __launch_bounds__(256) void fused_gather_gemm(const u16* __restrict__ y16,
                                                         const int* __restrict__ contrib,
                                                         const float* __restrict__ wbary,
                                                         const int* __restrict__ angles,
                                                         const u16* __restrict__ k2c,
                                                         float* __restrict__ pb) {
    __shared__ __align__(16) u16 Bb[2][128 * BSTR];   // 20,480 B
    const int t = threadIdx.x;
    const int s  = blockIdx.x & 1;           // K-slice
    const int kcBeg = s * KSPLIT_CH;
    const int kcEnd = kcBeg + KSPLIT_CH;
    const int w = t >> 6, lane = t & 63;
    const int lrow = lane & 15, lq = lane >> 4;
    const int s_p = lq >> 1;                 // rd parity this lane owns
    const int h8  = (lq & 1) * 8;            // ch-half element offset
    const int m0 = (blockIdx.x >> 1) * 64;
    const int arow = m0 + w * 16 + lrow;     // GEMM row == gather row (same lane!)
    const int b_p = (arow >= NV);
    const int v_p = arow - b_p * NV;
    const u16* __restrict__ yb = y16 + (size_t)b_p * NVD * CH + h8;  // batch table + half
    const int mb0 = v_p * 192 + s_p * 3;     // meta element base; idx(kc) = mb0 + kc*6
    const int sn = t >> 1, sh = (t & 1) * 16;

    // pipeline state — ALL named scalars/vectors (no runtime-indexed arrays)
    int   cA0, cA1, cA2, aA0, aA1, aA2;  float wA0, wA1, wA2, vA0, vA1, vA2;  u32x4 gA0, gA1, gA2;
    int   cB0, cB1, cB2, aB0, aB1, aB2;  float wB0, wB1, wB2, vB0, vB1, vB2;  u32x4 gB0, gB1, gB2;
    int   cC0, cC1, cC2, aC0, aC1, aC2;  float wC0, wC1, wC2, vC0, vC1, vC2;  u32x4 gC0, gC1, gC2;
    u32x4 bne0, bne1, bno0, bno1;        // B staging regs (even / odd chunk parity)

    f32x4 acc[8];
    #pragma unroll
    for (int nt = 0; nt < 8; ++nt) acc[nt] = (f32x4){0.f, 0.f, 0.f, 0.f};

#define META_ISSUE(S, KC_) { const int o_ = mb0 + (KC_) * 6;                       \
    c##S##0 = contrib[o_]; c##S##1 = contrib[o_ + 1]; c##S##2 = contrib[o_ + 2];   \
    a##S##0 = angles[o_];  a##S##1 = angles[o_ + 1];  a##S##2 = angles[o_ + 2];    \
    w##S##0 = wbary[o_];   w##S##1 = wbary[o_ + 1];   w##S##2 = wbary[o_ + 2]; }

#define G_ISSUE(S, KC_) {                                                          \
    if ((KC_) < 32) {                                                              \
        g##S##0 = *(const u32x4*)(yb + (size_t)((unsigned)c##S##0 * 128u +         \
                                                (unsigned)a##S##0 * 16u));         \
        g##S##1 = *(const u32x4*)(yb + (size_t)((unsigned)c##S##1 * 128u +         \
                                                (unsigned)a##S##1 * 16u));         \
        g##S##2 = *(const u32x4*)(yb + (size_t)((unsigned)c##S##2 * 128u +         \
                                                (unsigned)a##S##2 * 16u));         \
        v##S##0 = w##S##0; v##S##1 = w##S##1; v##S##2 = w##S##2;                   \
    } else {                                                                       \
        g##S##0 = *(const u32x4*)(yb + (size_t)((unsigned)v_p * 128u +             \
                                      (unsigned)(2 * ((KC_) - 32) + s_p) * 16u));  \
    } }

#define COMBINE(S, KC_, A_) {                                                      \
    if ((KC_) < 32) {                                                              \
        float ac_[8];                                                              \
        _Pragma("unroll") for (int x_ = 0; x_ < 8; ++x_) ac_[x_] = 0.f;            \
        _Pragma("unroll")                                                          \
        for (int q_ = 0; q_ < 4; ++q_) {                                           \
            unsigned u0_ = g##S##0[q_], u1_ = g##S##1[q_], u2_ = g##S##2[q_];      \
            ac_[2 * q_]     += v##S##0 * __uint_as_float(u0_ << 16);               \
            ac_[2 * q_ + 1] += v##S##0 * __uint_as_float(u0_ & 0xffff0000u);       \
            ac_[2 * q_]     += v##S##1 * __uint_as_float(u1_ << 16);               \
            ac_[2 * q_ + 1] += v##S##1 * __uint_as_float(u1_ & 0xffff0000u);       \
            ac_[2 * q_]     += v##S##2 * __uint_as_float(u2_ << 16);               \
            ac_[2 * q_ + 1] += v##S##2 * __uint_as_float(u2_ & 0xffff0000u);       \
        }                                                                          \
        u32x4 o_;                                                                  \
        _Pragma("unroll") for (int q_ = 0; q_ < 4; ++q_)                           \
            o_[q_] = pack2bf(ac_[2 * q_], ac_[2 * q_ + 1]);                        \
        A_ = *(bf16x8*)&o_;                                                        \
    } else { u32x4 o_ = g##S##0; A_ = *(bf16x8*)&o_; } }

// Even-parity chunk: read Bb[0]; B-issue(KC+2, even) -> bne; B-write(KC+1, odd) from bno.
#define CHUNK_EV(S, KC_) {                                                              \
    __syncthreads();                                                                    \
    if ((KC_) + 2 < kcEnd) {                                                            \
        const u32x4* src_ = (const u32x4*)(k2c + (size_t)((KC_) + 2) * 4096 + sn * 32 + sh); \
        bne0 = src_[0]; bne1 = src_[1];                                                 \
    }                                                                                   \
    bf16x8 av_;                                                                         \
    COMBINE(S, KC_, av_);                                                               \
    if ((KC_) + 3 < kcEnd) G_ISSUE(S, (KC_) + 3);                                       \
    if ((KC_) + 6 < kcEnd && (KC_) + 6 < 32) META_ISSUE(S, (KC_) + 6);                  \
    {   bf16x8 bf_[8];                                                                  \
        _Pragma("unroll")                                                               \
        for (int nt_ = 0; nt_ < 8; ++nt_)                                               \
            bf_[nt_] = *(const bf16x8*)(&Bb[0][(nt_ * 16 + lrow) * BSTR + lq * 8]);     \
        _Pragma("unroll")                                                               \
        for (int nt_ = 0; nt_ < 8; ++nt_)                                               \
            acc[nt_] = __builtin_amdgcn_mfma_f32_16x16x32_bf16(av_, bf_[nt_], acc[nt_], 0, 0, 0); \
    }                                                                                   \
    if ((KC_) + 1 < kcEnd) {                                                            \
        u16* dst_ = &Bb[1][sn * BSTR + sh];                                             \
        *(u32x4*)(dst_)     = bno0;                                                     \
        *(u32x4*)(dst_ + 8) = bno1;                                                     \
    } }

// Odd-parity chunk: read Bb[1]; B-issue(KC+2, odd) -> bno; B-write(KC+1, even) from bne.
#define CHUNK_OD(S, KC_) {                                                              \
    __syncthreads();                                                                    \
    if ((KC_) + 2 < kcEnd) {                                                            \
        const u32x4* src_ = (const u32x4*)(k2c + (size_t)((KC_) + 2) * 4096 + sn * 32 + sh); \
        bno0 = src_[0]; bno1 = src_[1];                                                 \
    }                                                                                   \
    bf16x8 av_;                                                                         \
    COMBINE(S, KC_, av_);                                                               \
    if ((KC_) + 3 < kcEnd) G_ISSUE(S, (KC_) + 3);                                       \
    if ((KC_) + 6 < kcEnd && (KC_) + 6 < 32) META_ISSUE(S, (KC_) + 6);                  \
    {   bf16x8 bf_[8];                                                                  \
        _Pragma("unroll")                                                               \
        for (int nt_ = 0; nt_ < 8; ++nt_)                                               \
            bf_[nt_] = *(const bf16x8*)(&Bb[1][(nt_ * 16 + lrow) * BSTR + lq * 8]);     \
        _Pragma("unroll")                                                               \
        for (int nt_ = 0; nt_ < 8; ++nt_)                                               \
            acc[nt_] = __builtin_amdgcn_mfma_f32_16x16x32_bf16(av_, bf_[nt_], acc[nt_], 0, 0, 0); \
    }                                                                                   \
    if ((KC_) + 1 < kcEnd) {                                                            \
        u16* dst_ = &Bb[0][sn * BSTR + sh];                                             \
        *(u32x4*)(dst_)     = bne0;                                                     \
        *(u32x4*)(dst_ + 8) = bne1;                                                     \
    } }

    // ---- prologue: meta lead 6, gather lead 3, B(kcBeg) staged, B(kcBeg+1) in bno ----
    META_ISSUE(A, kcBeg + 0);
    META_ISSUE(B, kcBeg + 1);
    META_ISSUE(C, kcBeg + 2);
    {   // stage B(kcBeg) directly into Bb[0]
        const u32x4* src = (const u32x4*)(k2c + (size_t)kcBeg * 4096 + sn * 32 + sh);
        u32x4 b0 = src[0], b1 = src[1];
        u16* dst = &Bb[0][sn * BSTR + sh];
        *(u32x4*)(dst)     = b0;
        *(u32x4*)(dst + 8) = b1;
    }
    G_ISSUE(A, kcBeg + 0); META_ISSUE(A, kcBeg + 3);
    G_ISSUE(B, kcBeg + 1); META_ISSUE(B, kcBeg + 4);
    G_ISSUE(C, kcBeg + 2); META_ISSUE(C, kcBeg + 5);
    {   // B(kcBeg+1) -> bno (consumed by first even chunk's ds_write)
        const u32x4* src = (const u32x4*)(k2c + (size_t)(kcBeg + 1) * 4096 + sn * 32 + sh);
        bno0 = src[0]; bno1 = src[1];
    }

    // ---- main loop: 3 iterations x 6 chunks; slots rotate A,B,C; parity static ----
    for (int p = 0; p < 3; ++p) {
        const int base = kcBeg + 6 * p;     // always even
        CHUNK_EV(A, base + 0);
        CHUNK_OD(B, base + 1);
        CHUNK_EV(C, base + 2);
        CHUNK_OD(A, base + 3);
        CHUNK_EV(B, base + 4);
        CHUNK_OD(C, base + 5);
    }
#undef META_ISSUE
#undef G_ISSUE
#undef COMBINE
#undef CHUNK_EV
#undef CHUNK_OD

    // partial store, col-major pb[s][n][row]: f32x4 over 4 consecutive rows -> coalesced
    float* pbs = pb + (size_t)(s * 128) * MTOT;
    #pragma unroll
    for (int nt = 0; nt < 8; ++nt) {
        *(f32x4*)(pbs + (size_t)(nt * 16 + lrow) * MTOT + m0 + w * 16 + lq * 4) = acc[nt];
    }
}

// ---------------- E: combine K-slices + bias + relu + max over w ----------------
__global__ __launch_bounds__(256) void combine_max(const float* __restrict__ pb,
                                                   const float* __restrict__ bias,
                                                   float* __restrict__ out) {
    int tid = blockIdx.x * 256 + threadIdx.x;   // [0, 80000)
    if (tid >= 2 * MTOT) return;
    int row = tid >> 1, half = tid & 1;
    const float* p0 = pb + row;
    const float* p1 = pb + (size_t)128 * MTOT + row;
    float bs[8], m[8];
    #pragma unroll
    for (int j = 0; j < 8; ++j) { bs[j] = bias[half * 8 + j]; m[j] = 0.f; }
    #pragma unroll
    for (int w = 0; w < 8; ++w) {
        #pragma unroll
        for (int j = 0; j < 8; ++j) {
            int n = w * 16 + half * 8 + j;
            float v = p0[(size_t)n * MTOT] + p1[(size_t)n * MTOT] + bs[j];
            m[j] = fmaxf(m[j], v);
        }
    }
    float4 o0 = {m[0], m[1], m[2], m[3]};
    float4 o1 = {m[4], m[5], m[6], m[7]};
    float* dst = out + (size_t)row * NF + half * 8;
    *(float4*)(dst)     = o0;
    *(float4*)(dst + 4) = o1;
}

extern "C" void kernel_launch(void* const* d_in, const int* in_sizes, int n_in,
                              void* d_out, int out_size, void* d_ws, size_t ws_size,
                              hipStream_t stream) {
    const float* y      = (const float*)d_in[0];
    const int*   contrib= (const int*)d_in[1];
    const float* wbary  = (const float*)d_in[2];
    const int*   angles = (const int*)d_in[3];
    const float* kern   = (const float*)d_in[4];
    const float* ck     = (const float*)d_in[5];
    const float* bias   = (const float*)d_in[6];
    float* out = (float*)d_out;

    u16*   y16 = (u16*)((char*)d_ws + Y16_OFF_B);
    u16*   k2c = (u16*)((char*)d_ws + K2C_OFF_B);
    float* pb  = (float*)((char*)d_ws + PB_OFF_B);   // needs ws_size >= 51,494,912 B

    prep_k2<<<PREP_BLOCKS + K2_BLOCKS, 256, 0, stream>>>(y, y16, kern, ck, k2c);  // 1826 blocks
    fused_gather_gemm<<<2 * (MTOT / 64), 256, 0, stream>>>(y16, contrib, wbary, angles,
                                                           k2c, pb);              // 1250 blocks
    combine_max<<<(2 * MTOT + 255) / 256, 256, 0, stream>>>(pb, bias, out);       // 313 blocks
}

// Round 8
// 216.798 us; speedup vs baseline: 1.1523x; 1.1063x over previous
//
#include <hip/hip_runtime.h>

typedef unsigned short u16;
typedef __attribute__((ext_vector_type(4))) unsigned int u32x4;
typedef __attribute__((ext_vector_type(4))) float f32x4;
typedef __attribute__((ext_vector_type(8))) __bf16 bf16x8;

// Problem constants (fixed by the reference).
constexpr int BATCH = 2;
constexpr int NV    = 20000;
constexpr int ND    = 8;
constexpr int CH    = 16;
constexpr int NF    = 16;
constexpr int NVD   = NV * ND;        // 160000 rows of y_flat per batch
constexpr int NCHUNK = 36;            // 32 conv chunks + 4 center chunks (K=1152)
constexpr int MTOT  = BATCH * NV;     // 40000 GEMM rows
constexpr int BSTR  = 40;             // padded B row stride in bf16 (32+8)
constexpr int KSPLIT_CH = 18;         // chunks per K-slice (2 slices)
constexpr int TPB   = 313;            // tiles per batch (last tile has 32 valid rows)
constexpr int ITEMS_PB = TPB * 2;     // 626 work items (tile,slice) per batch group
constexpr int PREP_BLOCKS = 1250;
constexpr int K2_BLOCKS   = 576;
constexpr int MIDX_BLOCKS = 7500;     // 1,920,000 threads, 2 meta elements each

// ws layout (bytes):
//   [0, 10,240,000)              y16  : bf16 [B][NVD][CH]
//   [10,240,000, 10,534,912)     k2c  : bf16 [36][128][32]
//   [10,534,912, 25,894,912)     midx : int  [NV][64][3]  ((cn*8+an)*16 precomputed)
//   [25,894,912, 66,854,912)     pb   : f32  [2][128][40000] (K-slice partials)
constexpr size_t Y16_OFF_B  = 0;
constexpr size_t K2C_OFF_B  = 10240000;
constexpr size_t MIDX_OFF_B = 10534912;
constexpr size_t PB_OFF_B   = 25894912;   // total ws needed = 66,854,912 B

__device__ __forceinline__ u16 f2bf(float x) {
    unsigned int u = __float_as_uint(x);
    unsigned int r = (u + 0x7fffu + ((u >> 16) & 1u)) >> 16;   // RNE
    return (u16)r;
}
__device__ __forceinline__ unsigned int pack2bf(float a, float b) {
    return (unsigned int)f2bf(a) | ((unsigned int)f2bf(b) << 16);
}

// ---------------- P: merged prep (y->y16) + k2c build + midx prepass ----------------
__global__ __launch_bounds__(256) void prep_k2(const float* __restrict__ y,
                                               u16* __restrict__ y16,
                                               const float* __restrict__ kern,
                                               const float* __restrict__ ck,
                                               u16* __restrict__ k2c,
                                               const int* __restrict__ contrib,
                                               const int* __restrict__ angles,
                                               int* __restrict__ midx) {
    int bid = blockIdx.x;
    if (bid < PREP_BLOCKS) {
        int tid = bid * 256 + threadIdx.x;          // [0, 320000)
        const float4* src = (const float4*)(y + (size_t)tid * 16);
        float4 v0 = src[0], v1 = src[1], v2 = src[2], v3 = src[3];
        u32x4 lo = {pack2bf(v0.x, v0.y), pack2bf(v0.z, v0.w), pack2bf(v1.x, v1.y), pack2bf(v1.z, v1.w)};
        u32x4 hi = {pack2bf(v2.x, v2.y), pack2bf(v2.z, v2.w), pack2bf(v3.x, v3.y), pack2bf(v3.z, v3.w)};
        u16* yd = y16 + (size_t)tid * 16;
        *(u32x4*)(yd)     = lo;
        *(u32x4*)(yd + 8) = hi;
    } else if (bid < PREP_BLOCKS + K2_BLOCKS) {
        int e = (bid - PREP_BLOCKS) * 256 + threadIdx.x;   // [0, 36*4096)
        int i = e & 4095;
        int kc = e >> 12;
        int n = i >> 5, kk = i & 31;
        int k = kc * 32 + kk;
        int w = n >> 4, f = n & 15;
        float val;
        if (k < 1024) {
            int r = k >> 7, dd = (k >> 4) & 7, c = k & 15;
            int d = (dd - w) & 7;
            val = kern[((r * 8 + d) * 16 + c) * 16 + f];
        } else {
            int ke = k - 1024;
            int d = ke >> 4, c = ke & 15;
            val = (d == w) ? ck[c * 16 + f] : 0.f;
        }
        k2c[e] = f2bf(val);
    } else {
        // midx prepass: fold (contrib, angle) -> element offset (cn*8+an)*16
        size_t k = (size_t)(bid - (PREP_BLOCKS + K2_BLOCKS)) * 256 + threadIdx.x; // [0, 1.92M)
        int2 c = *(const int2*)(contrib + 2 * k);
        int2 a = *(const int2*)(angles + 2 * k);
        int2 m;
        m.x = c.x * 128 + a.x * 16;
        m.y = c.y * 128 + a.y * 16;
        *(int2*)(midx + 2 * k) = m;
    }
}

// ---------------- F: FUSED gather + barycentric + K-slice GEMM ----------------
// r7 lesson: bound by L2 request throughput — per-lane meta loads were ~3x the gather
// requests and 4x redundant. Fix: (a) meta staged to LDS cooperatively (coalesced,
// 4-ahead pipeline; lanes read via broadcast-friendly ds_read), (b) batch<->XCD
// partition (bid%8 heuristic): XCDs 0-3 do batch 0, 4-7 batch 1 -> per-L2 gather
// working set = one 5.12 MB table. 313 tiles/batch, last tile row-guarded.
// Gather pipeline depth 3 (slots A/B/C), all state in NAMED registers (rule #20).
__global__ __launch_bounds__(256) void fused_gather_gemm(const u16* __restrict__ y16,
                                                         const int* __restrict__ midx,
                                                         const float* __restrict__ wb,
                                                         const u16* __restrict__ k2c,
                                                         float* __restrict__ pb) {
    __shared__ __align__(16) u16 Bb[2][128 * BSTR];   // 20,480 B
    __shared__ __align__(8) int   Mi[2][384];         // meta idx, per-chunk dbuf
    __shared__ __align__(8) float Mw[2][384];         // meta weights
    const int bid = blockIdx.x;
    const int xcd = bid & 7;
    const int g   = xcd >> 2;                         // batch group (XCD 0-3 / 4-7)
    const int item = (bid >> 3) * 4 + (xcd & 3);
    if (item >= ITEMS_PB) return;
    const int tile = item >> 1;                       // 0..312
    const int s    = item & 1;                        // K-slice
    const int kcBeg = s * KSPLIT_CH, kcEnd = kcBeg + KSPLIT_CH;
    const int t = threadIdx.x;
    const int w = t >> 6, lane = t & 63;
    const int lrow = lane & 15, lq = lane >> 4;
    const int s_p = lq >> 1;                 // rd parity this lane owns
    const int h8  = (lq & 1) * 8;            // ch-half element offset
    const int rb  = tile * 64 + w * 16 + lrow;        // row within batch (may be >= NV)
    const int v_p = rb < NV ? rb : NV - 1;            // clamped vertex
    const int m0  = g * NV + tile * 64;               // global row base
    const u16* __restrict__ yb = y16 + (size_t)g * NVD * CH + h8;
    const int sn = t >> 1, sh = (t & 1) * 16;
    // meta staging role: threads 0..191, thread t covers vertex t/3, pair t%3
    const bool stg = (t < 192);
    const int stg_v = t / 3, stg_p = t % 3;
    const int stg_vr = tile * 64 + stg_v;
    const size_t stg_base = (size_t)(stg_vr < NV ? stg_vr : NV - 1) * 192 + stg_p * 2;
    const int vloc6 = (w * 16 + lrow) * 6 + s_p * 3;  // lane's LDS meta base

    // pipeline state — ALL named (rule #20)
    u32x4 gA0, gA1, gA2, gB0, gB1, gB2, gC0, gC1, gC2;
    float vA0, vA1, vA2, vB0, vB1, vB2, vC0, vC1, vC2;
    u32x4 bne0, bne1, bno0, bno1;
    int2   mi0, mi1;  float2 mw0, mw1;                // meta staging regs (2 sets)

    f32x4 acc[8];
    #pragma unroll
    for (int nt = 0; nt < 8; ++nt) acc[nt] = (f32x4){0.f, 0.f, 0.f, 0.f};

#define MLOAD(SET, KC_) if (stg && (KC_) < 32 && (KC_) < kcEnd) {                  \
    mi##SET = *(const int2*)(midx + stg_base + (size_t)(KC_) * 6);                 \
    mw##SET = *(const float2*)(wb + stg_base + (size_t)(KC_) * 6); }

#define MWRITE(SET, P_, KC_) if (stg && (KC_) < 32 && (KC_) < kcEnd) {             \
    *(int2*)(&Mi[P_][stg_v * 6 + stg_p * 2]) = mi##SET;                            \
    *(float2*)(&Mw[P_][stg_v * 6 + stg_p * 2]) = mw##SET; }

#define G_LDS(S, KC_, P_) {                                                        \
    if ((KC_) < 32) {                                                              \
        const int i0_ = Mi[P_][vloc6], i1_ = Mi[P_][vloc6 + 1], i2_ = Mi[P_][vloc6 + 2]; \
        v##S##0 = Mw[P_][vloc6]; v##S##1 = Mw[P_][vloc6 + 1]; v##S##2 = Mw[P_][vloc6 + 2]; \
        g##S##0 = *(const u32x4*)(yb + (unsigned)i0_);                             \
        g##S##1 = *(const u32x4*)(yb + (unsigned)i1_);                             \
        g##S##2 = *(const u32x4*)(yb + (unsigned)i2_);                             \
    } else {                                                                       \
        g##S##0 = *(const u32x4*)(yb + (size_t)((unsigned)v_p * 128u +             \
                                      (unsigned)(2 * ((KC_) - 32) + s_p) * 16u));  \
    } }

#define PRO_G(S, KC_) {                                                            \
    size_t mo_ = (size_t)v_p * 192 + (KC_) * 6 + s_p * 3;                          \
    const int i0_ = midx[mo_], i1_ = midx[mo_ + 1], i2_ = midx[mo_ + 2];           \
    v##S##0 = wb[mo_]; v##S##1 = wb[mo_ + 1]; v##S##2 = wb[mo_ + 2];               \
    g##S##0 = *(const u32x4*)(yb + (unsigned)i0_);                                 \
    g##S##1 = *(const u32x4*)(yb + (unsigned)i1_);                                 \
    g##S##2 = *(const u32x4*)(yb + (unsigned)i2_); }

#define COMBINE(S, KC_, A_) {                                                      \
    if ((KC_) < 32) {                                                              \
        float ac_[8];                                                              \
        _Pragma("unroll") for (int x_ = 0; x_ < 8; ++x_) ac_[x_] = 0.f;            \
        _Pragma("unroll")                                                          \
        for (int q_ = 0; q_ < 4; ++q_) {                                           \
            unsigned u0_ = g##S##0[q_], u1_ = g##S##1[q_], u2_ = g##S##2[q_];      \
            ac_[2 * q_]     += v##S##0 * __uint_as_float(u0_ << 16);               \
            ac_[2 * q_ + 1] += v##S##0 * __uint_as_float(u0_ & 0xffff0000u);       \
            ac_[2 * q_]     += v##S##1 * __uint_as_float(u1_ << 16);               \
            ac_[2 * q_ + 1] += v##S##1 * __uint_as_float(u1_ & 0xffff0000u);       \
            ac_[2 * q_]     += v##S##2 * __uint_as_float(u2_ << 16);               \
            ac_[2 * q_ + 1] += v##S##2 * __uint_as_float(u2_ & 0xffff0000u);       \
        }                                                                          \
        u32x4 o_;                                                                  \
        _Pragma("unroll") for (int q_ = 0; q_ < 4; ++q_)                           \
            o_[q_] = pack2bf(ac_[2 * q_], ac_[2 * q_ + 1]);                        \
        A_ = *(bf16x8*)&o_;                                                        \
    } else { u32x4 o_ = g##S##0; A_ = *(bf16x8*)&o_; } }

// Even chunk: reads Bb[0], meta-LDS parity 1; writes meta(KC+4)->Mi[0] from set0,
// loads set1=meta(KC+5); B-issue(KC+2)->bne; B-write(KC+1) from bno.
#define CHUNK_EV(S, KC_) {                                                              \
    __syncthreads();                                                                    \
    MLOAD(1, (KC_) + 5)                                                                 \
    if ((KC_) + 2 < kcEnd) {                                                            \
        const u32x4* src_ = (const u32x4*)(k2c + (size_t)((KC_) + 2) * 4096 + sn * 32 + sh); \
        bne0 = src_[0]; bne1 = src_[1];                                                 \
    }                                                                                   \
    bf16x8 av_;                                                                         \
    COMBINE(S, KC_, av_);                                                               \
    if ((KC_) + 3 < kcEnd) G_LDS(S, (KC_) + 3, 1)                                       \
    MWRITE(0, 0, (KC_) + 4)                                                             \
    {   bf16x8 bf_[8];                                                                  \
        _Pragma("unroll")                                                               \
        for (int nt_ = 0; nt_ < 8; ++nt_)                                               \
            bf_[nt_] = *(const bf16x8*)(&Bb[0][(nt_ * 16 + lrow) * BSTR + lq * 8]);     \
        _Pragma("unroll")                                                               \
        for (int nt_ = 0; nt_ < 8; ++nt_)                                               \
            acc[nt_] = __builtin_amdgcn_mfma_f32_16x16x32_bf16(av_, bf_[nt_], acc[nt_], 0, 0, 0); \
    }                                                                                   \
    {   u16* dst_ = &Bb[1][sn * BSTR + sh];                                             \
        *(u32x4*)(dst_)     = bno0;                                                     \
        *(u32x4*)(dst_ + 8) = bno1;                                                     \
    } }

// Odd chunk: reads Bb[1], meta-LDS parity 0; writes meta(KC+4)->Mi[1] from set1,
// loads set0=meta(KC+5); B-issue(KC+2)->bno; B-write(KC+1) from bne.
#define CHUNK_OD(S, KC_) {                                                              \
    __syncthreads();                                                                    \
    MLOAD(0, (KC_) + 5)                                                                 \
    if ((KC_) + 2 < kcEnd) {                                                            \
        const u32x4* src_ = (const u32x4*)(k2c + (size_t)((KC_) + 2) * 4096 + sn * 32 + sh); \
        bno0 = src_[0]; bno1 = src_[1];                                                 \
    }                                                                                   \
    bf16x8 av_;                                                                         \
    COMBINE(S, KC_, av_);                                                               \
    if ((KC_) + 3 < kcEnd) G_LDS(S, (KC_) + 3, 0)                                       \
    MWRITE(1, 1, (KC_) + 4)                                                             \
    {   bf16x8 bf_[8];                                                                  \
        _Pragma("unroll")                                                               \
        for (int nt_ = 0; nt_ < 8; ++nt_)                                               \
            bf_[nt_] = *(const bf16x8*)(&Bb[1][(nt_ * 16 + lrow) * BSTR + lq * 8]);     \
        _Pragma("unroll")                                                               \
        for (int nt_ = 0; nt_ < 8; ++nt_)                                               \
            acc[nt_] = __builtin_amdgcn_mfma_f32_16x16x32_bf16(av_, bf_[nt_], acc[nt_], 0, 0, 0); \
    }                                                                                   \
    if ((KC_) + 1 < kcEnd) {                                                            \
        u16* dst_ = &Bb[0][sn * BSTR + sh];                                             \
        *(u32x4*)(dst_)     = bne0;                                                     \
        *(u32x4*)(dst_ + 8) = bne1;                                                     \
    } }

    // ---- prologue ----
    PRO_G(A, kcBeg + 0);                    // per-lane direct meta+gathers, one-time
    PRO_G(B, kcBeg + 1);
    PRO_G(C, kcBeg + 2);
    {   // stage B(kcBeg) -> Bb[0]
        const u32x4* src = (const u32x4*)(k2c + (size_t)kcBeg * 4096 + sn * 32 + sh);
        u32x4 b0 = src[0], b1 = src[1];
        u16* dst = &Bb[0][sn * BSTR + sh];
        *(u32x4*)(dst)     = b0;
        *(u32x4*)(dst + 8) = b1;
    }
    if (stg) {   // stage meta(kcBeg+3) -> Mi[1]/Mw[1]  (kcBeg+3 <= 21 < 32 always)
        int2   tmi = *(const int2*)(midx + stg_base + (size_t)(kcBeg + 3) * 6);
        float2 tmw = *(const float2*)(wb + stg_base + (size_t)(kcBeg + 3) * 6);
        *(int2*)(&Mi[1][stg_v * 6 + stg_p * 2]) = tmi;
        *(float2*)(&Mw[1][stg_v * 6 + stg_p * 2]) = tmw;
    }
    MLOAD(0, kcBeg + 4)                     // preload set0 (written at first EV chunk)
    {   // B(kcBeg+1) -> bno (consumed by first EV chunk's ds_write)
        const u32x4* src = (const u32x4*)(k2c + (size_t)(kcBeg + 1) * 4096 + sn * 32 + sh);
        bno0 = src[0]; bno1 = src[1];
    }

    // ---- main loop: 3 x 6 chunks; slots rotate A,B,C; parities static ----
    for (int p = 0; p < 3; ++p) {
        const int base = kcBeg + 6 * p;     // always even
        CHUNK_EV(A, base + 0);
        CHUNK_OD(B, base + 1);
        CHUNK_EV(C, base + 2);
        CHUNK_OD(A, base + 3);
        CHUNK_EV(B, base + 4);
        CHUNK_OD(C, base + 5);
    }
#undef MLOAD
#undef MWRITE
#undef G_LDS
#undef PRO_G
#undef COMBINE
#undef CHUNK_EV
#undef CHUNK_OD

    // partial store, col-major pb[s][n][row]; guard rows beyond batch (last tile)
    const bool mval = (tile * 64 + w * 16 + lq * 4) < NV;
    if (mval) {
        float* pbs = pb + (size_t)(s * 128) * MTOT;
        #pragma unroll
        for (int nt = 0; nt < 8; ++nt) {
            *(f32x4*)(pbs + (size_t)(nt * 16 + lrow) * MTOT + m0 + w * 16 + lq * 4) = acc[nt];
        }
    }
}

// ---------------- E: combine K-slices + bias + relu + max over w ----------------
__global__ __launch_bounds__(256) void combine_max(const float* __restrict__ pb,
                                                   const float* __restrict__ bias,
                                                   float* __restrict__ out) {
    int tid = blockIdx.x * 256 + threadIdx.x;   // [0, 80000)
    if (tid >= 2 * MTOT) return;
    int row = tid >> 1, half = tid & 1;
    const float* p0 = pb + row;
    const float* p1 = pb + (size_t)128 * MTOT + row;
    float bs[8], m[8];
    #pragma unroll
    for (int j = 0; j < 8; ++j) { bs[j] = bias[half * 8 + j]; m[j] = 0.f; }
    #pragma unroll
    for (int w = 0; w < 8; ++w) {
        #pragma unroll
        for (int j = 0; j < 8; ++j) {
            int n = w * 16 + half * 8 + j;
            float v = p0[(size_t)n * MTOT] + p1[(size_t)n * MTOT] + bs[j];
            m[j] = fmaxf(m[j], v);
        }
    }
    float4 o0 = {m[0], m[1], m[2], m[3]};
    float4 o1 = {m[4], m[5], m[6], m[7]};
    float* dst = out + (size_t)row * NF + half * 8;
    *(float4*)(dst)     = o0;
    *(float4*)(dst + 4) = o1;
}

extern "C" void kernel_launch(void* const* d_in, const int* in_sizes, int n_in,
                              void* d_out, int out_size, void* d_ws, size_t ws_size,
                              hipStream_t stream) {
    const float* y      = (const float*)d_in[0];
    const int*   contrib= (const int*)d_in[1];
    const float* wbary  = (const float*)d_in[2];
    const int*   angles = (const int*)d_in[3];
    const float* kern   = (const float*)d_in[4];
    const float* ck     = (const float*)d_in[5];
    const float* bias   = (const float*)d_in[6];
    float* out = (float*)d_out;

    u16*   y16  = (u16*)((char*)d_ws + Y16_OFF_B);
    u16*   k2c  = (u16*)((char*)d_ws + K2C_OFF_B);
    int*   midx = (int*)((char*)d_ws + MIDX_OFF_B);
    float* pb   = (float*)((char*)d_ws + PB_OFF_B);   // needs ws_size >= 66,854,912 B

    prep_k2<<<PREP_BLOCKS + K2_BLOCKS + MIDX_BLOCKS, 256, 0, stream>>>(
        y, y16, kern, ck, k2c, contrib, angles, midx);                     // 9326 blocks
    fused_gather_gemm<<<1256, 256, 0, stream>>>(y16, midx, wbary, k2c, pb);
    combine_max<<<(2 * MTOT + 255) / 256, 256, 0, stream>>>(pb, bias, out); // 313 blocks
}